// Round 19
// baseline (137.550 us; speedup 1.0000x reference)
//
#include <hip/hip_runtime.h>
#include <cstdint>

#define NTOK 65536
#define DIM 240
#define KP 256
#define NMETA 576
#define NGB 1024         // gating blocks (64 tokens each)

typedef short bf16x8 __attribute__((ext_vector_type(8)));
typedef float f32x16 __attribute__((ext_vector_type(16)));
typedef unsigned int u32x4 __attribute__((ext_vector_type(4)));
typedef unsigned int u32x2 __attribute__((ext_vector_type(2)));

union U16B { uint4 u; u32x4 c; bf16x8 v; };
union U8B { ushort4 s; u32x2 c; };

__device__ __forceinline__ unsigned short f2bf(float x) {
  unsigned int u = __float_as_uint(x);
  u += 0x7fffu + ((u >> 16) & 1u);     // RNE
  return (unsigned short)(u >> 16);
}

// DPP move helpers (VALU pipe). 0xB1 = quad_perm xor1, 0x4E = quad_perm xor2,
// 0x128 = row_ror:8 (== xor8 within a 16-lane row).
template<int CTRL>
__device__ __forceinline__ float dppf(float v) {
  return __int_as_float(__builtin_amdgcn_update_dpp(0, __float_as_int(v), CTRL, 0xF, 0xF, true));
}
template<int CTRL>
__device__ __forceinline__ unsigned dppu(unsigned v) {
  return (unsigned)__builtin_amdgcn_update_dpp(0, (int)v, CTRL, 0xF, 0xF, true);
}
__device__ __forceinline__ bool pgt(unsigned a, unsigned b) {
  float fa = __uint_as_float(a & ~7u), fb = __uint_as_float(b & ~7u);
  return (fa != fb) ? (fa > fb) : ((a & 7u) < (b & 7u));
}
template<int CTRL>
__device__ __forceinline__ void top2round(unsigned& a1, unsigned& a2) {
  unsigned b1 = dppu<CTRL>(a1), b2 = dppu<CTRL>(a2);
  bool g = pgt(a1, b1);
  unsigned n1 = g ? a1 : b1;
  unsigned lo = g ? b1 : a1;
  unsigned m2 = pgt(a2, b2) ? a2 : b2;
  a2 = pgt(lo, m2) ? lo : m2;
  a1 = n1;
}

// ---------------- kernel 1: gating (DPP reduce) + bf16 xb write (NT), 1024 blocks x 64 tok.
// Also packs expert weights granule-major WbT[e][g32][col256][16B] (fused prep_w).
__global__ __launch_bounds__(512) void gating(const float* __restrict__ x,
                                              const float* __restrict__ gw,
                                              const float* __restrict__ gb,
                                              const float* __restrict__ ew,
                                              unsigned short* __restrict__ WbT,
                                              unsigned short* __restrict__ xb,
                                              unsigned char* __restrict__ pairid,
                                              float2* __restrict__ wpair,
                                              int* __restrict__ hist2d) {
  __shared__ __align__(16) float gwT[8][DIM];
  __shared__ int hist[64];
  // fused prep_w: gid enumerates e(8) x n(256) x k-quad(64) = 131072 slots
  {
    const int gid = blockIdx.x * 512 + threadIdx.x;
    if (gid < 131072) {
      const int k0 = (gid & 63) << 2;
      const int nn = (gid >> 6) & 255;
      const int e = gid >> 14;
      ushort4 v = {0, 0, 0, 0};
      if (nn < DIM && k0 < DIM) {
        const float* wrow = ew + (e * DIM + nn) * DIM;
        v.x = f2bf(wrow[k0]); v.y = f2bf(wrow[k0 + 1]);
        v.z = f2bf(wrow[k0 + 2]); v.w = f2bf(wrow[k0 + 3]);
      }
      *(ushort4*)&WbT[((size_t)(e * 32 + (k0 >> 3)) * 256 + nn) * 8 + (k0 & 7)] = v;
    }
  }
  for (int i = threadIdx.x; i < 8 * DIM; i += 512) gwT[i & 7][i >> 3] = gw[i];
  if (threadIdx.x < 64) hist[threadIdx.x] = 0;
  __syncthreads();
  const int lane = threadIdx.x & 63;
  const int w = threadIdx.x >> 6;
  const bool act = lane < 60;
  float4 g[8];
#pragma unroll
  for (int e = 0; e < 8; ++e)
    g[e] = act ? *(const float4*)(&gwT[e][lane * 4]) : make_float4(0.f, 0.f, 0.f, 0.f);
  const int elane = 4 * (lane & 1) + 2 * ((lane >> 1) & 1) + ((lane >> 3) & 1);
  const float gbl = gb[elane];
  const int tbase = blockIdx.x * 64 + w * 8;
  for (int it = 0; it < 8; ++it) {
    const int t = tbase + it;
    float4 xv = act ? *(const float4*)(x + (size_t)t * DIM + lane * 4)
                    : make_float4(0.f, 0.f, 0.f, 0.f);
    float p[8];
#pragma unroll
    for (int e = 0; e < 8; ++e)
      p[e] = xv.x * g[e].x + xv.y * g[e].y + xv.z * g[e].z + xv.w * g[e].w;
    float q4[4];
#pragma unroll
    for (int i = 0; i < 4; ++i) {
      float lo = p[i] + dppf<0xB1>(p[i]);
      float hi = p[i + 4] + dppf<0xB1>(p[i + 4]);
      q4[i] = (lane & 1) ? hi : lo;
    }
    float q2[2];
#pragma unroll
    for (int i = 0; i < 2; ++i) {
      float lo = q4[i] + dppf<0x4E>(q4[i]);
      float hi = q4[i + 2] + dppf<0x4E>(q4[i + 2]);
      q2[i] = (lane & 2) ? hi : lo;
    }
    float lo = q2[0] + dppf<0x128>(q2[0]);
    float hi = q2[1] + dppf<0x128>(q2[1]);
    float s = (lane & 8) ? hi : lo;
    s += __shfl_xor(s, 4);
    s += __shfl_xor(s, 16);
    s += __shfl_xor(s, 32);
    s += gbl;
    unsigned a1 = (__float_as_uint(s) & ~7u) | (unsigned)elane;
    unsigned a2 = (0xFF800000u & ~7u) | 7u;
    top2round<0xB1>(a1, a2);
    top2round<0x4E>(a1, a2);
    top2round<0x128>(a1, a2);
    U8B vv; vv.s = make_ushort4(0, 0, 0, 0);
    if (act) {
      vv.s.x = f2bf(xv.x); vv.s.y = f2bf(xv.y); vv.s.z = f2bf(xv.z); vv.s.w = f2bf(xv.w);
    }
    __builtin_nontemporal_store(vv.c, (u32x2*)(xb + (size_t)t * KP + lane * 4));
    if (lane == 0) {
      const int i1 = a1 & 7, i2 = a2 & 7;
      const float l1 = __uint_as_float(a1 & ~7u), l2 = __uint_as_float(a2 & ~7u);
      const float qq = expf(l2 - l1);
      const float w1 = 1.f / (1.f + qq);
      const float w2 = qq / (1.f + qq);
      const int ea = (i1 < i2) ? i1 : i2, eb2 = (i1 < i2) ? i2 : i1;
      const float wa = (i1 < i2) ? w1 : w2, wb2 = (i1 < i2) ? w2 : w1;
      const int pp = ea * 8 + eb2;
      pairid[t] = (unsigned char)pp;
      wpair[t] = make_float2(wa, wb2);
      atomicAdd(&hist[pp], 1);                  // LDS only
    }
  }
  __syncthreads();
  if (threadIdx.x < 64) hist2d[blockIdx.x * 64 + threadIdx.x] = hist[threadIdx.x];
}

// ---------------- kernel 2: per-pair exclusive scan over 1024 block-hists (64 blocks)
__global__ __launch_bounds__(1024) void scan1_k(const int* __restrict__ hist2d,
                                                int* __restrict__ lbase2d,
                                                int* __restrict__ cnt) {
  __shared__ int s[NGB];
  const int p = blockIdx.x, tid = threadIdx.x;
  const int v = hist2d[tid * 64 + p];
  s[tid] = v;
  __syncthreads();
  for (int off = 1; off < NGB; off <<= 1) {
    int tv = (tid >= off) ? s[tid - off] : 0;
    __syncthreads();
    s[tid] += tv;
    __syncthreads();
  }
  lbase2d[tid * 64 + p] = s[tid] - v;
  if (tid == NGB - 1) cnt[p] = s[tid];
}

// ---------------- kernel 3: pair starts + tile meta (128-token tiles)
__global__ void scan2_k(const int* __restrict__ cnt, int* __restrict__ start,
                        int4* __restrict__ meta) {
  __shared__ int sc[64], sstart[64], stile[64], stot;
  const int tid = threadIdx.x;
  sc[tid] = cnt[tid];
  __syncthreads();
  if (tid == 0) {
    int a = 0, ta = 0;
    for (int p = 0; p < 64; ++p) { sstart[p] = a; stile[p] = ta; a += sc[p]; ta += (sc[p] + 127) >> 7; }
    stot = ta;
  }
  __syncthreads();
  start[tid] = sstart[tid];
  const int c = sc[tid], e0 = tid >> 3, e1 = tid & 7;
  for (int i = 0; (i << 7) < c; ++i)
    meta[stile[tid] + i] = make_int4(e0, e1, sstart[tid] + (i << 7), min(128, c - (i << 7)));
  for (int j = stot + tid; j < NMETA; j += 64)
    meta[j] = make_int4(0, 0, 0, 0);
}

// ---------------- kernel 4: route only (no data copy): wsorted/tokord (1024 x 64)
__global__ __launch_bounds__(64) void route_k(const unsigned char* __restrict__ pairid,
                                              const float2* __restrict__ wpair,
                                              const int* __restrict__ start,
                                              const int* __restrict__ lbase2d,
                                              float2* __restrict__ wsorted,
                                              int* __restrict__ tokord) {
  __shared__ int lcnt[64];
  const int b = blockIdx.x, tid = threadIdx.x;
  lcnt[tid] = 0;
  __syncthreads();
  const int t = b * 64 + tid;
  const int p = pairid[t];
  const int rank = atomicAdd(&lcnt[p], 1);       // LDS only
  const int pos = start[p] + lbase2d[b * 64 + p] + rank;
  wsorted[pos] = wpair[t];
  tokord[pos] = t;
}

// ---------------- kernel 5: pair-sparse GEMM — A gathered via NONTEMPORAL reg loads
// (keeps W L2-resident), W register-streamed from WbT, 2 barriers, 2 blocks/CU.
// Block = 128 tok x 128 cols (half) x both experts; 512 thr; wave = 32 tok x 64 col.
__global__ __launch_bounds__(512, 4) void moe_gemm_pair(const unsigned short* __restrict__ xb,
                                                        const unsigned short* __restrict__ WbT,
                                                        const float* __restrict__ ebias,
                                                        const float2* __restrict__ wsorted,
                                                        const int* __restrict__ tokord,
                                                        const int4* __restrict__ meta,
                                                        float* __restrict__ out) {
  extern __shared__ __align__(16) char smem[];
  // A: [g32][row128][16B] = 64KB (granules 30,31 are the zero-pad in xb rows)
  int* ptok = (int*)(smem + 65536);              // 512 B
  float2* wab = (float2*)(smem + 66048);         // 1 KB

  const int4 m = meta[blockIdx.x >> 1];
  const int n = m.w;
  if (n == 0) return;
  const int ch = blockIdx.x & 1;                 // column half
  const int tid = threadIdx.x, lane = tid & 63, wid = tid >> 6;
  const int tq = wid >> 1, cg = wid & 1;         // 4 token-quarters x 2 col-groups
  const int l31 = lane & 31, hi = lane >> 5;

  if (tid < 128) {
    const int idx = m.z + (tid < n ? tid : n - 1);
    ptok[tid] = tokord[idx];
    wab[tid] = wsorted[idx];
  }
  __syncthreads();

  // A gather once via NT register loads (no L2 allocation -> W stays L2-hot).
  // slot i = tid + 512j: row = i&127 (== tid&127), granule = (i>>7) = (tid>>7)+4j
  u32x4 areg[8];
#pragma unroll
  for (int j = 0; j < 8; ++j) {
    const int i = tid + 512 * j;
    areg[j] = __builtin_nontemporal_load(
        (const u32x4*)((const char*)xb + (size_t)ptok[i & 127] * 512 + ((i >> 7) << 4)));
  }

  // W frag pointers: frag(it, cf, e) at wbase_e + it*8192 + cf*512  (g = 2it+hi)
  const int colb = ch * 128 + cg * 64 + l31;
  const char* wbase0 = (const char*)WbT + (size_t)m.x * 131072 + (size_t)hi * 4096 + (size_t)colb * 16;
  const char* wbase1 = (const char*)WbT + (size_t)m.y * 131072 + (size_t)hi * 4096 + (size_t)colb * 16;

  // preload W for it=0 (overlaps the A gather in flight)
  uint4 w0[4], w1[4];
  w0[0] = *(const uint4*)(wbase0);
  w0[1] = *(const uint4*)(wbase1);
  w0[2] = *(const uint4*)(wbase0 + 512);
  w0[3] = *(const uint4*)(wbase1 + 512);

  // write gathered A to LDS (linear dest, same layout as before)
#pragma unroll
  for (int j = 0; j < 8; ++j)
    *(u32x4*)(smem + (size_t)(tid + 512 * j) * 16) = areg[j];
  __syncthreads();                               // the only other barrier

  f32x16 accA[2] = {}, accB[2] = {};
  const char* apt = smem + (size_t)hi * 2048 + (size_t)(tq * 32 + l31) * 16;  // + it*4096

#pragma unroll
  for (int it = 0; it < 16; ++it) {              // K = 256 (g 30,31 are zeros)
    if (it < 15) {                               // prefetch next W frags (dbuf)
      const size_t o = (size_t)(it + 1) * 8192;
      uint4* nxt = (it & 1) ? w0 : w1;           // constant after unroll
      nxt[0] = *(const uint4*)(wbase0 + o);
      nxt[1] = *(const uint4*)(wbase1 + o);
      nxt[2] = *(const uint4*)(wbase0 + o + 512);
      nxt[3] = *(const uint4*)(wbase1 + o + 512);
    }
    const uint4* cur = (it & 1) ? w1 : w0;
    U16B a; a.u = *(const uint4*)(apt + (size_t)it * 4096);
    U16B b0, b1, b2, b3;
    b0.u = cur[0]; b1.u = cur[1]; b2.u = cur[2]; b3.u = cur[3];
    accA[0] = __builtin_amdgcn_mfma_f32_32x32x16_bf16(a.v, b0.v, accA[0], 0, 0, 0);
    accB[0] = __builtin_amdgcn_mfma_f32_32x32x16_bf16(a.v, b1.v, accB[0], 0, 0, 0);
    accA[1] = __builtin_amdgcn_mfma_f32_32x32x16_bf16(a.v, b2.v, accA[1], 0, 0, 0);
    accB[1] = __builtin_amdgcn_mfma_f32_32x32x16_bf16(a.v, b3.v, accB[1], 0, 0, 0);
  }

  // epilogue: out[tok, col] = wa*(P_A + b_A[col]) + wb*(P_B + b_B[col]); nontemporal
#pragma unroll
  for (int cf = 0; cf < 2; ++cf) {
    const int col = ch * 128 + cg * 64 + cf * 32 + l31;
    if (col < DIM) {
      const float be0 = ebias[m.x * DIM + col];
      const float be1 = ebias[m.y * DIM + col];
#pragma unroll
      for (int r = 0; r < 16; ++r) {
        const int rw = tq * 32 + (r & 3) + ((r >> 2) << 3) + (hi << 2);
        if (rw < n) {
          const float2 w2 = wab[rw];
          __builtin_nontemporal_store(
              w2.x * (accA[cf][r] + be0) + w2.y * (accB[cf][r] + be1),
              &out[(size_t)ptok[rw] * DIM + col]);
        }
      }
    }
  }
}

extern "C" void kernel_launch(void* const* d_in, const int* in_sizes, int n_in,
                              void* d_out, int out_size, void* d_ws, size_t ws_size,
                              hipStream_t stream) {
  const float* x  = (const float*)d_in[0];
  const float* gw = (const float*)d_in[1];
  const float* gb = (const float*)d_in[2];
  const float* ew = (const float*)d_in[3];
  const float* eb = (const float*)d_in[4];
  float* out = (float*)d_out;

  // workspace layout (~36.6 MB)
  char* ws = (char*)d_ws;
  unsigned short* WbT  = (unsigned short*)ws;                          // 1 MB
  unsigned short* xb   = (unsigned short*)(ws + 1048576);              // 33 MB (unsorted bf16 [NTOK][256])
  float2*         wpr  = (float2*)(ws + 34734080);                     // 512 KB
  float2*         wsr  = (float2*)(ws + 35258368);                     // sorted weights
  int*            tord = (int*)(ws + 35784704);                        // sorted token ids
  unsigned char*  pid  = (unsigned char*)(ws + 36047872);              // 64 KB
  int*            h2d  = (int*)(ws + 36113408);                        // 256 KB  [1024][64]
  int*            lb2d = (int*)(ws + 36375552);                        // 256 KB  [1024][64]
  int*            cnt  = (int*)(ws + 36637696);                        // 256 B
  int*            strt = (int*)(ws + 36637952);                        // 256 B
  int4*           meta = (int4*)(ws + 36638208);                       // 9.2 KB

  hipFuncSetAttribute((const void*)moe_gemm_pair, hipFuncAttributeMaxDynamicSharedMemorySize, 67072);

  gating<<<NGB, 512, 0, stream>>>(x, gw, gb, ew, WbT, xb, pid, wpr, h2d);
  scan1_k<<<64, NGB, 0, stream>>>(h2d, lb2d, cnt);
  scan2_k<<<1, 64, 0, stream>>>(cnt, strt, meta);
  route_k<<<NGB, 64, 0, stream>>>(pid, wpr, strt, lb2d, wsr, tord);
  moe_gemm_pair<<<2 * NMETA, 512, 67072, stream>>>(xb, WbT, eb, wsr, tord, meta, out);
}

// Round 20
// 92.031 us; speedup vs baseline: 1.4946x; 1.4946x over previous
//
#include <hip/hip_runtime.h>
#include <cstdint>

#define NTOK 65536
#define DIM 240
#define KP 256
#define NMETA 576
#define NGB 1024         // gating blocks (64 tokens each)

typedef short bf16x8 __attribute__((ext_vector_type(8)));
typedef float f32x16 __attribute__((ext_vector_type(16)));
typedef unsigned int u32x4 __attribute__((ext_vector_type(4)));

union U16B { uint4 u; u32x4 c; bf16x8 v; };

__device__ __forceinline__ unsigned short f2bf(float x) {
  unsigned int u = __float_as_uint(x);
  u += 0x7fffu + ((u >> 16) & 1u);     // RNE
  return (unsigned short)(u >> 16);
}

// DPP move helpers (VALU pipe). 0xB1 = quad_perm xor1, 0x4E = quad_perm xor2,
// 0x128 = row_ror:8 (== xor8 within a 16-lane row).
template<int CTRL>
__device__ __forceinline__ float dppf(float v) {
  return __int_as_float(__builtin_amdgcn_update_dpp(0, __float_as_int(v), CTRL, 0xF, 0xF, true));
}
template<int CTRL>
__device__ __forceinline__ unsigned dppu(unsigned v) {
  return (unsigned)__builtin_amdgcn_update_dpp(0, (int)v, CTRL, 0xF, 0xF, true);
}
__device__ __forceinline__ bool pgt(unsigned a, unsigned b) {
  float fa = __uint_as_float(a & ~7u), fb = __uint_as_float(b & ~7u);
  return (fa != fb) ? (fa > fb) : ((a & 7u) < (b & 7u));
}
template<int CTRL>
__device__ __forceinline__ void top2round(unsigned& a1, unsigned& a2) {
  unsigned b1 = dppu<CTRL>(a1), b2 = dppu<CTRL>(a2);
  bool g = pgt(a1, b1);
  unsigned n1 = g ? a1 : b1;
  unsigned lo = g ? b1 : a1;
  unsigned m2 = pgt(a2, b2) ? a2 : b2;
  a2 = pgt(lo, m2) ? lo : m2;
  a1 = n1;
}

// ---------------- kernel 1: gating (DPP reduce) + bf16 xb write, 1024 blocks x 64 tok.
// Also packs expert weights granule-major WbT[e][g32][col256][16B] (fused prep_w).
__global__ __launch_bounds__(512) void gating(const float* __restrict__ x,
                                              const float* __restrict__ gw,
                                              const float* __restrict__ gb,
                                              const float* __restrict__ ew,
                                              unsigned short* __restrict__ WbT,
                                              unsigned short* __restrict__ xb,
                                              unsigned char* __restrict__ pairid,
                                              float2* __restrict__ wpair,
                                              int* __restrict__ hist2d) {
  __shared__ __align__(16) float gwT[8][DIM];
  __shared__ int hist[64];
  // fused prep_w: gid enumerates e(8) x n(256) x k-quad(64) = 131072 slots
  {
    const int gid = blockIdx.x * 512 + threadIdx.x;
    if (gid < 131072) {
      const int k0 = (gid & 63) << 2;
      const int nn = (gid >> 6) & 255;
      const int e = gid >> 14;
      ushort4 v = {0, 0, 0, 0};
      if (nn < DIM && k0 < DIM) {
        const float* wrow = ew + (e * DIM + nn) * DIM;
        v.x = f2bf(wrow[k0]); v.y = f2bf(wrow[k0 + 1]);
        v.z = f2bf(wrow[k0 + 2]); v.w = f2bf(wrow[k0 + 3]);
      }
      *(ushort4*)&WbT[((size_t)(e * 32 + (k0 >> 3)) * 256 + nn) * 8 + (k0 & 7)] = v;
    }
  }
  for (int i = threadIdx.x; i < 8 * DIM; i += 512) gwT[i & 7][i >> 3] = gw[i];
  if (threadIdx.x < 64) hist[threadIdx.x] = 0;
  __syncthreads();
  const int lane = threadIdx.x & 63;
  const int w = threadIdx.x >> 6;
  const bool act = lane < 60;
  float4 g[8];
#pragma unroll
  for (int e = 0; e < 8; ++e)
    g[e] = act ? *(const float4*)(&gwT[e][lane * 4]) : make_float4(0.f, 0.f, 0.f, 0.f);
  const int elane = 4 * (lane & 1) + 2 * ((lane >> 1) & 1) + ((lane >> 3) & 1);
  const float gbl = gb[elane];
  const int tbase = blockIdx.x * 64 + w * 8;
  for (int it = 0; it < 8; ++it) {
    const int t = tbase + it;
    float4 xv = act ? *(const float4*)(x + (size_t)t * DIM + lane * 4)
                    : make_float4(0.f, 0.f, 0.f, 0.f);
    float p[8];
#pragma unroll
    for (int e = 0; e < 8; ++e)
      p[e] = xv.x * g[e].x + xv.y * g[e].y + xv.z * g[e].z + xv.w * g[e].w;
    float q4[4];
#pragma unroll
    for (int i = 0; i < 4; ++i) {
      float lo = p[i] + dppf<0xB1>(p[i]);
      float hi = p[i + 4] + dppf<0xB1>(p[i + 4]);
      q4[i] = (lane & 1) ? hi : lo;
    }
    float q2[2];
#pragma unroll
    for (int i = 0; i < 2; ++i) {
      float lo = q4[i] + dppf<0x4E>(q4[i]);
      float hi = q4[i + 2] + dppf<0x4E>(q4[i + 2]);
      q2[i] = (lane & 2) ? hi : lo;
    }
    float lo = q2[0] + dppf<0x128>(q2[0]);
    float hi = q2[1] + dppf<0x128>(q2[1]);
    float s = (lane & 8) ? hi : lo;
    s += __shfl_xor(s, 4);
    s += __shfl_xor(s, 16);
    s += __shfl_xor(s, 32);
    s += gbl;
    unsigned a1 = (__float_as_uint(s) & ~7u) | (unsigned)elane;
    unsigned a2 = (0xFF800000u & ~7u) | 7u;
    top2round<0xB1>(a1, a2);
    top2round<0x4E>(a1, a2);
    top2round<0x128>(a1, a2);
    ushort4 v = {0, 0, 0, 0};
    if (act) { v.x = f2bf(xv.x); v.y = f2bf(xv.y); v.z = f2bf(xv.z); v.w = f2bf(xv.w); }
    *(ushort4*)(xb + (size_t)t * KP + lane * 4) = v;
    if (lane == 0) {
      const int i1 = a1 & 7, i2 = a2 & 7;
      const float l1 = __uint_as_float(a1 & ~7u), l2 = __uint_as_float(a2 & ~7u);
      const float qq = expf(l2 - l1);
      const float w1 = 1.f / (1.f + qq);
      const float w2 = qq / (1.f + qq);
      const int ea = (i1 < i2) ? i1 : i2, eb2 = (i1 < i2) ? i2 : i1;
      const float wa = (i1 < i2) ? w1 : w2, wb2 = (i1 < i2) ? w2 : w1;
      const int pp = ea * 8 + eb2;
      pairid[t] = (unsigned char)pp;
      wpair[t] = make_float2(wa, wb2);
      atomicAdd(&hist[pp], 1);                  // LDS only
    }
  }
  __syncthreads();
  if (threadIdx.x < 64) hist2d[blockIdx.x * 64 + threadIdx.x] = hist[threadIdx.x];
}

// ---------------- kernel 2: per-pair exclusive scan over 1024 block-hists (64 blocks)
__global__ __launch_bounds__(1024) void scan1_k(const int* __restrict__ hist2d,
                                                int* __restrict__ lbase2d,
                                                int* __restrict__ cnt) {
  __shared__ int s[NGB];
  const int p = blockIdx.x, tid = threadIdx.x;
  const int v = hist2d[tid * 64 + p];
  s[tid] = v;
  __syncthreads();
  for (int off = 1; off < NGB; off <<= 1) {
    int tv = (tid >= off) ? s[tid - off] : 0;
    __syncthreads();
    s[tid] += tv;
    __syncthreads();
  }
  lbase2d[tid * 64 + p] = s[tid] - v;
  if (tid == NGB - 1) cnt[p] = s[tid];
}

// ---------------- kernel 3: pair starts + tile meta (128-token tiles)
__global__ void scan2_k(const int* __restrict__ cnt, int* __restrict__ start,
                        int4* __restrict__ meta) {
  __shared__ int sc[64], sstart[64], stile[64], stot;
  const int tid = threadIdx.x;
  sc[tid] = cnt[tid];
  __syncthreads();
  if (tid == 0) {
    int a = 0, ta = 0;
    for (int p = 0; p < 64; ++p) { sstart[p] = a; stile[p] = ta; a += sc[p]; ta += (sc[p] + 127) >> 7; }
    stot = ta;
  }
  __syncthreads();
  start[tid] = sstart[tid];
  const int c = sc[tid], e0 = tid >> 3, e1 = tid & 7;
  for (int i = 0; (i << 7) < c; ++i)
    meta[stile[tid] + i] = make_int4(e0, e1, sstart[tid] + (i << 7), min(128, c - (i << 7)));
  for (int j = stot + tid; j < NMETA; j += 64)
    meta[j] = make_int4(0, 0, 0, 0);
}

// ---------------- kernel 4: route only (no data copy): wsorted/tokord (1024 x 64)
__global__ __launch_bounds__(64) void route_k(const unsigned char* __restrict__ pairid,
                                              const float2* __restrict__ wpair,
                                              const int* __restrict__ start,
                                              const int* __restrict__ lbase2d,
                                              float2* __restrict__ wsorted,
                                              int* __restrict__ tokord) {
  __shared__ int lcnt[64];
  const int b = blockIdx.x, tid = threadIdx.x;
  lcnt[tid] = 0;
  __syncthreads();
  const int t = b * 64 + tid;
  const int p = pairid[t];
  const int rank = atomicAdd(&lcnt[p], 1);       // LDS only
  const int pos = start[p] + lbase2d[b * 64 + p] + rank;
  wsorted[pos] = wpair[t];
  tokord[pos] = t;
}

// ---------------- kernel 5: pair-sparse GEMM — A gathered SINGLE-TOUCH COALESCED via
// NT reg loads (each 128B line fetched exactly once; no L2 allocation -> W stays
// L2-hot), scatter to LDS [row][g^row&31] (4-way conflicts both sides). W register-
// streamed from WbT (normal loads, L2-resident). 2 barriers, 2 blocks/CU.
__global__ __launch_bounds__(512, 4) void moe_gemm_pair(const unsigned short* __restrict__ xb,
                                                        const unsigned short* __restrict__ WbT,
                                                        const float* __restrict__ ebias,
                                                        const float2* __restrict__ wsorted,
                                                        const int* __restrict__ tokord,
                                                        const int4* __restrict__ meta,
                                                        float* __restrict__ out) {
  extern __shared__ __align__(16) char smem[];
  // A: [row128][g32][16B] with granule XOR-swizzle g^(row&31) = 64KB
  int* ptok = (int*)(smem + 65536);              // 512 B
  float2* wab = (float2*)(smem + 66048);         // 1 KB

  const int4 m = meta[blockIdx.x >> 1];
  const int n = m.w;
  if (n == 0) return;
  const int ch = blockIdx.x & 1;                 // column half
  const int tid = threadIdx.x, lane = tid & 63, wid = tid >> 6;
  const int tq = wid >> 1, cg = wid & 1;         // 4 token-quarters x 2 col-groups
  const int l31 = lane & 31, hi = lane >> 5;

  if (tid < 128) {
    const int idx = m.z + (tid < n ? tid : n - 1);
    ptok[tid] = tokord[idx];
    wab[tid] = wsorted[idx];
  }
  __syncthreads();

  // A gather once: slot i = tid+512j -> row = i>>5, g = i&31. 32 consecutive lanes
  // read one row's contiguous 512B (4 lines, each fetched exactly once). NT-safe.
  u32x4 areg[8];
#pragma unroll
  for (int j = 0; j < 8; ++j) {
    const int i = tid + 512 * j;
    areg[j] = __builtin_nontemporal_load(
        (const u32x4*)((const char*)xb + (size_t)ptok[i >> 5] * 512 + ((i & 31) << 4)));
  }

  // W frag pointers: frag(it, cf, e) at wbase_e + it*8192 + cf*512  (g = 2it+hi)
  const int colb = ch * 128 + cg * 64 + l31;
  const char* wbase0 = (const char*)WbT + (size_t)m.x * 131072 + (size_t)hi * 4096 + (size_t)colb * 16;
  const char* wbase1 = (const char*)WbT + (size_t)m.y * 131072 + (size_t)hi * 4096 + (size_t)colb * 16;

  // preload W for it=0 (overlaps the A gather in flight)
  uint4 w0[4], w1[4];
  w0[0] = *(const uint4*)(wbase0);
  w0[1] = *(const uint4*)(wbase1);
  w0[2] = *(const uint4*)(wbase0 + 512);
  w0[3] = *(const uint4*)(wbase1 + 512);

  // scatter gathered A to LDS: dest = (row*32 + (g ^ (row&31))) * 16
#pragma unroll
  for (int j = 0; j < 8; ++j) {
    const int i = tid + 512 * j;
    const int row = i >> 5, gg = i & 31;
    *(u32x4*)(smem + (((row << 5) + (gg ^ (row & 31))) << 4)) = areg[j];
  }
  __syncthreads();                               // the only other barrier

  f32x16 accA[2] = {}, accB[2] = {};
  const int arow = tq * 32 + l31;                // this lane's A row (row&31 == l31)
  const char* abase = smem + ((size_t)arow << 9);

#pragma unroll
  for (int it = 0; it < 16; ++it) {              // K = 256 (g 30,31 are zeros)
    if (it < 15) {                               // prefetch next W frags (dbuf)
      const size_t o = (size_t)(it + 1) * 8192;
      uint4* nxt = (it & 1) ? w0 : w1;           // constant after unroll
      nxt[0] = *(const uint4*)(wbase0 + o);
      nxt[1] = *(const uint4*)(wbase1 + o);
      nxt[2] = *(const uint4*)(wbase0 + o + 512);
      nxt[3] = *(const uint4*)(wbase1 + o + 512);
    }
    const uint4* cur = (it & 1) ? w1 : w0;
    U16B a; a.u = *(const uint4*)(abase + (((2 * it + hi) ^ l31) << 4));
    U16B b0, b1, b2, b3;
    b0.u = cur[0]; b1.u = cur[1]; b2.u = cur[2]; b3.u = cur[3];
    accA[0] = __builtin_amdgcn_mfma_f32_32x32x16_bf16(a.v, b0.v, accA[0], 0, 0, 0);
    accB[0] = __builtin_amdgcn_mfma_f32_32x32x16_bf16(a.v, b1.v, accB[0], 0, 0, 0);
    accA[1] = __builtin_amdgcn_mfma_f32_32x32x16_bf16(a.v, b2.v, accA[1], 0, 0, 0);
    accB[1] = __builtin_amdgcn_mfma_f32_32x32x16_bf16(a.v, b3.v, accB[1], 0, 0, 0);
  }

  // epilogue: out[tok, col] = wa*(P_A + b_A[col]) + wb*(P_B + b_B[col]); nontemporal
#pragma unroll
  for (int cf = 0; cf < 2; ++cf) {
    const int col = ch * 128 + cg * 64 + cf * 32 + l31;
    if (col < DIM) {
      const float be0 = ebias[m.x * DIM + col];
      const float be1 = ebias[m.y * DIM + col];
#pragma unroll
      for (int r = 0; r < 16; ++r) {
        const int rw = tq * 32 + (r & 3) + ((r >> 2) << 3) + (hi << 2);
        if (rw < n) {
          const float2 w2 = wab[rw];
          __builtin_nontemporal_store(
              w2.x * (accA[cf][r] + be0) + w2.y * (accB[cf][r] + be1),
              &out[(size_t)ptok[rw] * DIM + col]);
        }
      }
    }
  }
}

extern "C" void kernel_launch(void* const* d_in, const int* in_sizes, int n_in,
                              void* d_out, int out_size, void* d_ws, size_t ws_size,
                              hipStream_t stream) {
  const float* x  = (const float*)d_in[0];
  const float* gw = (const float*)d_in[1];
  const float* gb = (const float*)d_in[2];
  const float* ew = (const float*)d_in[3];
  const float* eb = (const float*)d_in[4];
  float* out = (float*)d_out;

  // workspace layout (~36.6 MB)
  char* ws = (char*)d_ws;
  unsigned short* WbT  = (unsigned short*)ws;                          // 1 MB
  unsigned short* xb   = (unsigned short*)(ws + 1048576);              // 33 MB (unsorted bf16 [NTOK][256])
  float2*         wpr  = (float2*)(ws + 34734080);                     // 512 KB
  float2*         wsr  = (float2*)(ws + 35258368);                     // sorted weights
  int*            tord = (int*)(ws + 35784704);                        // sorted token ids
  unsigned char*  pid  = (unsigned char*)(ws + 36047872);              // 64 KB
  int*            h2d  = (int*)(ws + 36113408);                        // 256 KB  [1024][64]
  int*            lb2d = (int*)(ws + 36375552);                        // 256 KB  [1024][64]
  int*            cnt  = (int*)(ws + 36637696);                        // 256 B
  int*            strt = (int*)(ws + 36637952);                        // 256 B
  int4*           meta = (int4*)(ws + 36638208);                       // 9.2 KB

  hipFuncSetAttribute((const void*)moe_gemm_pair, hipFuncAttributeMaxDynamicSharedMemorySize, 67072);

  gating<<<NGB, 512, 0, stream>>>(x, gw, gb, ew, WbT, xb, pid, wpr, h2d);
  scan1_k<<<64, NGB, 0, stream>>>(h2d, lb2d, cnt);
  scan2_k<<<1, 64, 0, stream>>>(cnt, strt, meta);
  route_k<<<NGB, 64, 0, stream>>>(pid, wpr, strt, lb2d, wsr, tord);
  moe_gemm_pair<<<2 * NMETA, 512, 67072, stream>>>(xb, WbT, eb, wsr, tord, meta, out);
}